// Round 13
// baseline (234.868 us; speedup 1.0000x reference)
//
#include <hip/hip_runtime.h>
#include <math.h>

#define NN 256

typedef float f4nat __attribute__((ext_vector_type(4)));   // native vec for nontemporal

// ---- workspace layout (float offsets) ----
#define OFF_T0    0        // [256][128] float4 {P0B, V0x, V0y, V0z}
#define OFF_TW    131072   // [256][32]  float4 {PW, VWx, VWy, VWz}
#define OFF_T1A   163840   // [256][64]  float4 {A1k0, A1k1, A1k2, P1B}
#define OFF_T1B   229376   // [256][64]  float4 {U1x, U1y, U1z, 0}
#define OFF_S     294912   // [256][32]   s_in[a] @ Wm1[64:192]
#define OFF_E     303104   // [33][32]    embed_tbl @ Wm1[0:32]
#define OFF_CSP   305152   // [256]       csilu partial sums
#define TBL_F4    73728    // float4 count of T0..T1B region (294912/4)

__device__ __forceinline__ void nt_store4(float* p, float x, float y, float z, float w){
    f4nat v = {x, y, z, w};
    __builtin_nontemporal_store(v, (f4nat*)p);
}

__device__ __forceinline__ float my_erfinv(float x){
    float w = -logf((1.0f - x) * (1.0f + x));
    float p;
    if (w < 5.0f) {
        w = w - 2.5f;
        p = 2.81022636e-08f;
        p = 3.43273939e-07f + p*w;
        p = -3.5233877e-06f + p*w;
        p = -4.39150654e-06f + p*w;
        p = 0.00021858087f  + p*w;
        p = -0.00125372503f + p*w;
        p = -0.00417768164f + p*w;
        p = 0.246640727f    + p*w;
        p = 1.50140941f     + p*w;
    } else {
        w = sqrtf(w) - 3.0f;
        p = -0.000200214257f;
        p = 0.000100950558f + p*w;
        p = 0.00134934322f  + p*w;
        p = -0.00367342844f + p*w;
        p = 0.00573950773f  + p*w;
        p = -0.0076224613f  + p*w;
        p = 0.00943887047f  + p*w;
        p = 1.00167406f     + p*w;
        p = 2.83297682f     + p*w;
    }
    return p * x;
}

// grid = 512: blocks [0,256) build per-node tables; [256,512) csilu partials.
__global__ __launch_bounds__(256) void precompute_kernel(
    const float* __restrict__ feat, const float* __restrict__ W0,
    const float* __restrict__ W1, const float* __restrict__ tbl,
    const float* __restrict__ Wm1, float* __restrict__ ws)
{
    int b = blockIdx.x, t = threadIdx.x;
    __shared__ float s_l[128], v_l[192];
    __shared__ float P0B_l[128], V0_l[3][128];
    __shared__ float red[256];

    if (b >= NN){
        int bi = b - NN;
        int lo = bi * 391;
        int hi = lo + 391; if (hi > 100001) hi = 100001;
        float acc = 0.f;
        for (int i = lo + t; i < hi; i += 256){
            float u = -0.999999f + (float)i * (1.999998f / 100000.0f);
            float z = 1.41421356237f * my_erfinv(u);
            float s = z / (1.0f + __expf(-z));
            acc += s * s;
        }
        red[t] = acc;
        __syncthreads();
        for (int off = 128; off >= 1; off >>= 1){
            if (t < off) red[t] += red[t + off];
            __syncthreads();
        }
        if (t == 0) ws[OFF_CSP + bi] = red[0];
        return;
    }

    for (int idx = t; idx < 320; idx += 256){
        float val = feat[b*320 + idx];
        if (idx < 128) s_l[idx] = val; else v_l[idx-128] = val;
    }
    __syncthreads();
    if (t < 128){
        int o = t;
        float p0 = W0[192*128 + o];
        #pragma unroll 4
        for (int i = 0; i < 128; i++){
            float s = s_l[i];
            p0 += s * (W0[i*128 + o] + W0[(193+i)*128 + o]);
        }
        float v0d[3];
        for (int d = 0; d < 3; d++){
            float v0 = 0.f;
            #pragma unroll 4
            for (int c = 0; c < 64; c++) v0 += v_l[c*3+d] * W0[(128+c)*128 + o];
            v0d[d] = v0;
        }
        P0B_l[o] = p0;
        V0_l[0][o] = v0d[0]; V0_l[1][o] = v0d[1]; V0_l[2][o] = v0d[2];
        // nontemporal: don't leave dirty lines in this XCD's L2
        nt_store4(ws + OFF_T0 + (b*128 + o)*4, p0, v0d[0], v0d[1], v0d[2]);
    } else if (t < 192){
        int o = t - 128;
        float ac[3];
        for (int k = 0; k < 3; k++){
            float s = 0.f;
            #pragma unroll 4
            for (int c = 0; c < 64; c++){
                float v = v_l[c*3+k];
                s += v * (W1[c*64 + o] + W1[(257+c)*64 + o]);
            }
            ac[k] = s;
        }
        float p1 = W1[256*64 + o];
        #pragma unroll 4
        for (int c = 0; c < 128; c++) p1 += s_l[c] * W1[(64+c)*64 + o];
        float u1[3];
        for (int d = 0; d < 3; d++){
            float s = 0.f;
            #pragma unroll 4
            for (int c = 0; c < 64; c++) s += v_l[c*3+d] * W1[(192+c)*64 + o];
            u1[d] = 1.73205081f * s;
        }
        nt_store4(ws + OFF_T1A + (b*64 + o)*4, ac[0], ac[1], ac[2], p1);
        nt_store4(ws + OFF_T1B + (b*64 + o)*4, u1[0], u1[1], u1[2], 0.f);
    } else if (t < 224){
        int r = t - 192;
        float s = 0.f;
        #pragma unroll 4
        for (int i = 0; i < 128; i++) s += s_l[i] * Wm1[(64+i)*32 + r];
        ws[OFF_S + b*32 + r] = s;
        if (b < 33){
            float e = 0.f;
            #pragma unroll 4
            for (int k = 0; k < 32; k++) e += tbl[b*32 + k] * Wm1[k*32 + r];
            ws[OFF_E + b*32 + r] = e;
        }
    }
    __syncthreads();
    if (t < 32){
        int r = t;
        float pw = 0.f, vw0 = 0.f, vw1 = 0.f, vw2 = 0.f;
        #pragma unroll 4
        for (int o = 0; o < 128; o++){
            float w = Wm1[(192+o)*32 + r];
            pw  += P0B_l[o]  * w;
            vw0 += V0_l[0][o]* w;
            vw1 += V0_l[1][o]* w;
            vw2 += V0_l[2][o]* w;
        }
        nt_store4(ws + OFF_TW + (b*32 + r)*4, pw, vw0, vw1, vw2);
    }
}

// Main + epilogue: block a (512 threads = 16 pair-groups x 32 lanes) does the
// whole compacted b-list for receiver a, reduces in-block, then finishes the
// output row. Opens with a streaming warm sweep of the table region so the
// loop's table reads hit own-XCD L2 instead of serialized HBM demand misses.
__global__ __launch_bounds__(512) void mainepi_kernel(
    const float* __restrict__ feat,  const float* __restrict__ coord,
    const int* __restrict__ maskraw,
    const float* __restrict__ Wm1,   const float* __restrict__ Wm2,
    const float* __restrict__ Wout0, const float* __restrict__ Wout1,
    const float* __restrict__ Wmove,
    const float* __restrict__ ws,    float* __restrict__ out)
{
    const int a = blockIdx.x;
    const int t = threadIdx.x;
    const int g = t >> 5;
    const int l = t & 31;

    // big buffer: Wm2T [192][36] during loop; red/epilogue arrays after
    __shared__ __align__(16) float big[192*36];       // 27648 B
    __shared__ __align__(16) float WT1[32*36];        // [l][j] = Wm1[(32+j)*32+l]
    __shared__ __align__(16) float E_l[33*32];
    __shared__ __align__(16) float hsh[512];
    __shared__ __align__(16) float radsh[512];
    __shared__ float cxl[NN], cyl[NN], czl[NN];
    __shared__ int   blist[NN];
    __shared__ int   wcnt[4], wbase[4];
    __shared__ float cs_part[4];
    __shared__ int   na_sh, bflag_sh, maska_sh;
    __shared__ float invc_sh;

    // ---- warm sweep: stream the table region into this XCD's L2 ----
    {
        const float4* tb = (const float4*)(ws + OFF_T0);
        float wsum = 0.f;
        for (int idx = t; idx < TBL_F4; idx += 512){
            float4 v = tb[idx];
            wsum += v.x + v.y + v.z + v.w;
        }
        asm volatile("" :: "v"(wsum));   // keep live; no side effect
    }

    // ---- stage LDS ----
    for (int idx = t; idx < 6144; idx += 512){
        int r = idx / 192, o = idx - r*192;
        big[o*36 + r] = Wm2[idx];
    }
    for (int idx = t; idx < 1024; idx += 512){
        int j = idx >> 5, l2 = idx & 31;
        WT1[l2*36 + j] = Wm1[1024 + idx];
    }
    for (int idx = t; idx < 1056; idx += 512) E_l[idx] = ws[OFF_E + idx];

    if (t == 0) bflag_sh = 0;
    __syncthreads();
    if (t < 64 && (maskraw[t] & 0xFFFFFFFE)) bflag_sh = 1;
    float cs_acc = (t < NN) ? ws[OFF_CSP + t] : 0.f;
    __syncthreads();
    const bool bytemode = bflag_sh != 0;

    int m_t = 0, pfx = 0;
    if (t < NN){
        if (bytemode){
            unsigned int w = (unsigned int)maskraw[t >> 2];
            m_t = ((w >> ((t & 3) * 8)) & 0xFFu) != 0;
        } else {
            m_t = maskraw[t] != 0;
        }
        if (t == a) maska_sh = m_t;
        unsigned long long bal = __ballot(m_t != 0);
        int lane = t & 63;
        pfx = __popcll(bal & ((1ull << lane) - 1ull));
        if (lane == 0) wcnt[t >> 6] = __popcll(bal);
        #pragma unroll
        for (int off = 32; off >= 1; off >>= 1) cs_acc += __shfl_xor(cs_acc, off);
        if (lane == 0) cs_part[t >> 6] = cs_acc;
    }
    __syncthreads();
    if (t == 0){
        int s = 0;
        for (int w = 0; w < 4; w++){ wbase[w] = s; s += wcnt[w]; }
        na_sh = s;
        float cstot = cs_part[0] + cs_part[1] + cs_part[2] + cs_part[3];
        invc_sh = 1.0f / sqrtf(cstot / 100001.0f);
    }
    __syncthreads();
    if (t < NN && m_t) blist[wbase[t >> 6] + pfx] = t;
    __syncthreads();
    const int na = na_sh;
    for (int idx = t; idx < na; idx += 512){
        int bb = blist[idx];
        cxl[idx] = coord[bb*3+0];
        cyl[idx] = coord[bb*3+1];
        czl[idx] = coord[bb*3+2];
    }
    __syncthreads();

    const float inv_c = invc_sh;
    const bool mask_a = maska_sh != 0;
    const float ca0 = coord[a*3+0], ca1 = coord[a*3+1], ca2 = coord[a*3+2];
    const float sar = ws[OFF_S + a*32 + l];

    const float ISC   = 0.055814557f;  // 1/sqrt(321)
    const float IS320 = 0.055901699f;  // 1/sqrt(320)

    float acc0[4] = {0.f,0.f,0.f,0.f};
    float acc1[2][3] = {{0.f,0.f,0.f},{0.f,0.f,0.f}};

    const int cnt = mask_a ? na : 0;
    const int iters = (cnt + 15) >> 4;

    const float4* T0  = (const float4*)(ws + OFF_T0);
    const float4* TW  = (const float4*)(ws + OFF_TW);
    const float4* T1A = (const float4*)(ws + OFF_T1A);
    const float4* T1B = (const float4*)(ws + OFF_T1B);
    const float4* Wm2T4 = (const float4*)big;
    const float4* WT14  = (const float4*)WT1;

    for (int i = 0; i < iters; i++){
        int il = i*16 + g;
        bool active = il < cnt;
        int idx = active ? il : 0;
        int bb = blist[idx];
        float cmf = active ? 1.0f : 0.0f;

        float vx = ca0 - cxl[idx], vy = ca1 - cyl[idx], vz = ca2 - czl[idx];
        float nsq = vx*vx + vy*vy + vz*vz;
        float dist = sqrtf(nsq == 0.0f ? 1.0f : nsq);
        float sh1x = 1.73205081f*vx, sh1y = 1.73205081f*vy, sh1z = 1.73205081f*vz;
        float s20 = 3.87298335f*vx*vz;
        float s21 = 3.87298335f*vx*vy;
        float s22 = 2.23606798f*(vy*vy - 0.5f*(vx*vx + vz*vz));
        float s23 = 3.87298335f*vy*vz;
        float s24 = 1.93649167f*(vz*vz - vx*vx);
        float Txx = -s22*0.182574186f - s24*0.316227766f;
        float Tyy =  s22*0.365148372f;
        float Tzz = -s22*0.182574186f + s24*0.316227766f;
        float Txy =  s21*0.316227766f;
        float Txz =  s20*0.316227766f;
        float Tyz =  s23*0.316227766f;

        float m0v[4];
        #pragma unroll
        for (int j = 0; j < 4; j++){
            float4 t0 = T0[bb*128 + l + 32*j];
            m0v[j] = t0.x + vx*t0.y + vy*t0.z + vz*t0.w;
        }

        float vcen = 0.727272727f * (float)(l + 1);
        float ddr = (dist - vcen) * 1.375f;
        float rl = __expf(-ddr*ddr) * 0.892857143f * cmf;
        radsh[g*32 + l] = rl;
        float radw = 0.f;
        {
            const float4* rv = (const float4*)radsh + g*8;
            const float4* wv = WT14 + l*9;
            #pragma unroll
            for (int j4 = 0; j4 < 8; j4++){
                float4 r4 = rv[j4];
                float4 w4 = wv[j4];
                radw += r4.x*w4.x + r4.y*w4.y + r4.z*w4.z + r4.w*w4.w;
            }
        }

        int ir = a - bb;
        if (ir > 16 || ir < -16) ir = 0;
        if (!active) ir = 0;
        ir += 16;
        float4 tw = TW[bb*32 + l];
        float msgblk = tw.x + vx*tw.y + vy*tw.z + vz*tw.w;
        float pre = (E_l[ir*32 + l] + sar + radw + msgblk*ISC) * IS320;
        float h = pre / (1.0f + __expf(-pre)) * inv_c;
        hsh[g*32 + l] = h;

        float gg[6] = {0,0,0,0,0,0};
        {
            const float4* hv = (const float4*)hsh + g*8;
            #pragma unroll
            for (int r4 = 0; r4 < 8; r4++){
                float4 h4 = hv[r4];
                #pragma unroll
                for (int k = 0; k < 6; k++){
                    float4 w4 = Wm2T4[(l + 32*k)*9 + r4];
                    gg[k] += h4.x*w4.x + h4.y*w4.y + h4.z*w4.z + h4.w*w4.w;
                }
            }
        }
        #pragma unroll
        for (int k = 0; k < 6; k++) gg[k] *= cmf;

        #pragma unroll
        for (int j = 0; j < 4; j++) acc0[j] += m0v[j] * gg[j];

        #pragma unroll
        for (int jj = 0; jj < 2; jj++){
            float4 a1 = T1A[bb*64 + l + 32*jj];
            float4 u1 = T1B[bb*64 + l + 32*jj];
            float gv = gg[4+jj];
            float m10 = a1.x + sh1x*a1.w + Txx*u1.x + Txy*u1.y + Txz*u1.z;
            float m11 = a1.y + sh1y*a1.w + Txy*u1.x + Tyy*u1.y + Tyz*u1.z;
            float m12 = a1.z + sh1z*a1.w + Txz*u1.x + Tyz*u1.y + Tzz*u1.z;
            acc1[jj][0] += m10 * gv;
            acc1[jj][1] += m11 * gv;
            acc1[jj][2] += m12 * gv;
        }
    }

    // wave-internal combine of the two 32-lane groups (same channels)
    #pragma unroll
    for (int j = 0; j < 4; j++) acc0[j] += __shfl_xor(acc0[j], 32);
    #pragma unroll
    for (int jj = 0; jj < 2; jj++)
        #pragma unroll
        for (int k = 0; k < 3; k++) acc1[jj][k] += __shfl_xor(acc1[jj][k], 32);

    __syncthreads();   // done with Wm2T; alias big[] for reductions/epilogue
    float* red0  = big;          // [8][128]
    float* red1  = big + 1024;   // [8][192]
    float* aggr  = big + 2560;   // [320]
    float* r0_l  = big + 2880;   // [128]
    float* r1_l  = big + 3008;   // [192]
    float* f1_l  = big + 3200;   // [192]
    float* stats = big + 3392;   // [8]

    const int wv = t >> 6;
    if ((t & 63) < 32){
        #pragma unroll
        for (int j = 0; j < 4; j++) red0[wv*128 + l + 32*j] = acc0[j];
        #pragma unroll
        for (int jj = 0; jj < 2; jj++)
            #pragma unroll
            for (int k = 0; k < 3; k++) red1[wv*192 + (l + 32*jj)*3 + k] = acc1[jj][k];
    }
    __syncthreads();

    const float cntv = mask_a ? (float)na : 0.0f;
    const float inv = (cntv > 1.0f) ? 1.0f / (cntv + 1e-6f) : 0.0f;
    const float SCALE = 0.055814557f * 0.176776695f;  // 1/sqrt(321)/sqrt(32)

    for (int idx = t; idx < 320; idx += 512){
        float s = 0.f;
        if (idx < 128){
            #pragma unroll
            for (int w = 0; w < 8; w++) s += red0[w*128 + idx];
        } else {
            #pragma unroll
            for (int w = 0; w < 8; w++) s += red1[w*192 + idx - 128];
        }
        aggr[idx] = s * SCALE * inv;
    }
    __syncthreads();

    if (t < 128){
        float f = 0.f;
        #pragma unroll 4
        for (int c = 0; c < 128; c++) f += aggr[c] * Wout0[c*128 + t];
        r0_l[t] = feat[a*320 + t] + f * 0.088388348f;   // 1/sqrt(128)
    } else if (t < 192){
        int o = t - 128;
        float fv0 = 0.f, fv1 = 0.f, fv2 = 0.f;
        #pragma unroll 4
        for (int c = 0; c < 64; c++){
            float w = Wout1[c*64 + o];
            fv0 += aggr[128 + c*3+0] * w;
            fv1 += aggr[128 + c*3+1] * w;
            fv2 += aggr[128 + c*3+2] * w;
        }
        fv0 *= 0.125f; fv1 *= 0.125f; fv2 *= 0.125f;
        f1_l[o*3+0] = fv0; f1_l[o*3+1] = fv1; f1_l[o*3+2] = fv2;
        r1_l[o*3+0] = feat[a*320 + 128 + o*3+0] + fv0;
        r1_l[o*3+1] = feat[a*320 + 128 + o*3+1] + fv1;
        r1_l[o*3+2] = feat[a*320 + 128 + o*3+2] + fv2;
    }
    __syncthreads();

    if (t < 64){
        float x0 = r0_l[t], x1 = r0_l[t+64];
        float s0 = x0 + x1, sq = x0*x0 + x1*x1;
        float y0 = r1_l[t*3], y1 = r1_l[t*3+1], y2 = r1_l[t*3+2];
        float s1 = y0*y0 + y1*y1 + y2*y2;
        float wm = Wmove[t];
        float d0 = f1_l[t*3+0]*wm, d1 = f1_l[t*3+1]*wm, d2 = f1_l[t*3+2]*wm;
        #pragma unroll
        for (int off = 32; off >= 1; off >>= 1){
            s0 += __shfl_xor(s0, off);
            sq += __shfl_xor(sq, off);
            s1 += __shfl_xor(s1, off);
            d0 += __shfl_xor(d0, off);
            d1 += __shfl_xor(d1, off);
            d2 += __shfl_xor(d2, off);
        }
        if (t == 0){
            float mu = s0 * (1.0f/128.0f);
            float var = sq * (1.0f/128.0f) - mu*mu;
            stats[0] = mu;
            stats[1] = 1.0f / sqrtf(var + 1e-6f);
            stats[2] = 1.0f / sqrtf(s1 * (1.0f/192.0f) + 1e-6f);
            stats[3] = d0; stats[4] = d1; stats[5] = d2;
        }
    }
    __syncthreads();

    float* orow = out + a*323;
    for (int idx = t; idx < 323; idx += 512){
        float v;
        if (idx < 128)      v = (r0_l[idx] - stats[0]) * stats[1];
        else if (idx < 320) v = r1_l[idx-128] * stats[2];
        else                v = coord[a*3 + (idx-320)] + 0.000125f * stats[3 + (idx-320)];
        orow[idx] = v;
    }
}

extern "C" void kernel_launch(void* const* d_in, const int* in_sizes, int n_in,
                              void* d_out, int out_size, void* d_ws, size_t ws_size,
                              hipStream_t stream)
{
    const float* feat  = (const float*)d_in[0];
    const float* coord = (const float*)d_in[1];
    const float* W0    = (const float*)d_in[2];
    const float* W1    = (const float*)d_in[3];
    const float* tbl   = (const float*)d_in[4];
    const float* Wm1   = (const float*)d_in[5];
    const float* Wm2   = (const float*)d_in[6];
    const float* Wout0 = (const float*)d_in[7];
    const float* Wout1 = (const float*)d_in[8];
    const float* Wmove = (const float*)d_in[9];
    const int*   mask  = (const int*)d_in[10];
    float* ws  = (float*)d_ws;
    float* out = (float*)d_out;

    precompute_kernel<<<NN + 256, 256, 0, stream>>>(feat, W0, W1, tbl, Wm1, ws);
    mainepi_kernel<<<NN, 512, 0, stream>>>(feat, coord, mask, Wm1, Wm2,
                                           Wout0, Wout1, Wmove, ws, out);
}

// Round 14
// 180.430 us; speedup vs baseline: 1.3017x; 1.3017x over previous
//
#include <hip/hip_runtime.h>
#include <math.h>

#define NN 256

// ---- workspace layout (float offsets) ----
#define OFF_T0    0        // [256][128] float4 {P0B, V0x, V0y, V0z}
#define OFF_TW    131072   // [256][32]  float4 {PW, VWx, VWy, VWz}
#define OFF_T1A   163840   // [256][64]  float4 {A1k0, A1k1, A1k2, P1B}
#define OFF_T1B   229376   // [256][64]  float4 {U1x, U1y, U1z, 0}
#define OFF_S     294912   // [256][32]   s_in[a] @ Wm1[64:192]
#define OFF_E     303104   // [33][32]    embed_tbl @ Wm1[0:32]
#define OFF_CSP   305152   // [256]       csilu partial sums

__device__ __forceinline__ float my_erfinv(float x){
    float w = -logf((1.0f - x) * (1.0f + x));
    float p;
    if (w < 5.0f) {
        w = w - 2.5f;
        p = 2.81022636e-08f;
        p = 3.43273939e-07f + p*w;
        p = -3.5233877e-06f + p*w;
        p = -4.39150654e-06f + p*w;
        p = 0.00021858087f  + p*w;
        p = -0.00125372503f + p*w;
        p = -0.00417768164f + p*w;
        p = 0.246640727f    + p*w;
        p = 1.50140941f     + p*w;
    } else {
        w = sqrtf(w) - 3.0f;
        p = -0.000200214257f;
        p = 0.000100950558f + p*w;
        p = 0.00134934322f  + p*w;
        p = -0.00367342844f + p*w;
        p = 0.00573950773f  + p*w;
        p = -0.0076224613f  + p*w;
        p = 0.00943887047f  + p*w;
        p = 1.00167406f     + p*w;
        p = 2.83297682f     + p*w;
    }
    return p * x;
}

// grid = 512: blocks [0,256) build per-node tables; [256,512) csilu partials.
__global__ __launch_bounds__(256) void precompute_kernel(
    const float* __restrict__ feat, const float* __restrict__ W0,
    const float* __restrict__ W1, const float* __restrict__ tbl,
    const float* __restrict__ Wm1, float* __restrict__ ws)
{
    int b = blockIdx.x, t = threadIdx.x;
    __shared__ float s_l[128], v_l[192];
    __shared__ float P0B_l[128], V0_l[3][128];
    __shared__ float red[256];

    if (b >= NN){
        int bi = b - NN;
        int lo = bi * 391;
        int hi = lo + 391; if (hi > 100001) hi = 100001;
        float acc = 0.f;
        for (int i = lo + t; i < hi; i += 256){
            float u = -0.999999f + (float)i * (1.999998f / 100000.0f);
            float z = 1.41421356237f * my_erfinv(u);
            float s = z / (1.0f + __expf(-z));
            acc += s * s;
        }
        red[t] = acc;
        __syncthreads();
        for (int off = 128; off >= 1; off >>= 1){
            if (t < off) red[t] += red[t + off];
            __syncthreads();
        }
        if (t == 0) ws[OFF_CSP + bi] = red[0];
        return;
    }

    for (int idx = t; idx < 320; idx += 256){
        float val = feat[b*320 + idx];
        if (idx < 128) s_l[idx] = val; else v_l[idx-128] = val;
    }
    __syncthreads();
    if (t < 128){
        int o = t;
        float p0 = W0[192*128 + o];
        #pragma unroll 4
        for (int i = 0; i < 128; i++){
            float s = s_l[i];
            p0 += s * (W0[i*128 + o] + W0[(193+i)*128 + o]);
        }
        float v0d[3];
        for (int d = 0; d < 3; d++){
            float v0 = 0.f;
            #pragma unroll 4
            for (int c = 0; c < 64; c++) v0 += v_l[c*3+d] * W0[(128+c)*128 + o];
            v0d[d] = v0;
        }
        P0B_l[o] = p0;
        V0_l[0][o] = v0d[0]; V0_l[1][o] = v0d[1]; V0_l[2][o] = v0d[2];
        ((float4*)(ws + OFF_T0))[b*128 + o] = make_float4(p0, v0d[0], v0d[1], v0d[2]);
    } else if (t < 192){
        int o = t - 128;
        float ac[3];
        for (int k = 0; k < 3; k++){
            float s = 0.f;
            #pragma unroll 4
            for (int c = 0; c < 64; c++){
                float v = v_l[c*3+k];
                s += v * (W1[c*64 + o] + W1[(257+c)*64 + o]);
            }
            ac[k] = s;
        }
        float p1 = W1[256*64 + o];
        #pragma unroll 4
        for (int c = 0; c < 128; c++) p1 += s_l[c] * W1[(64+c)*64 + o];
        float u1[3];
        for (int d = 0; d < 3; d++){
            float s = 0.f;
            #pragma unroll 4
            for (int c = 0; c < 64; c++) s += v_l[c*3+d] * W1[(192+c)*64 + o];
            u1[d] = 1.73205081f * s;
        }
        ((float4*)(ws + OFF_T1A))[b*64 + o] = make_float4(ac[0], ac[1], ac[2], p1);
        ((float4*)(ws + OFF_T1B))[b*64 + o] = make_float4(u1[0], u1[1], u1[2], 0.f);
    } else if (t < 224){
        int r = t - 192;
        float s = 0.f;
        #pragma unroll 4
        for (int i = 0; i < 128; i++) s += s_l[i] * Wm1[(64+i)*32 + r];
        ws[OFF_S + b*32 + r] = s;
        if (b < 33){
            float e = 0.f;
            #pragma unroll 4
            for (int k = 0; k < 32; k++) e += tbl[b*32 + k] * Wm1[k*32 + r];
            ws[OFF_E + b*32 + r] = e;
        }
    }
    __syncthreads();
    if (t < 32){
        int r = t;
        float pw = 0.f, vw0 = 0.f, vw1 = 0.f, vw2 = 0.f;
        #pragma unroll 4
        for (int o = 0; o < 128; o++){
            float w = Wm1[(192+o)*32 + r];
            pw  += P0B_l[o]  * w;
            vw0 += V0_l[0][o]* w;
            vw1 += V0_l[1][o]* w;
            vw2 += V0_l[2][o]* w;
        }
        ((float4*)(ws + OFF_TW))[b*32 + r] = make_float4(pw, vw0, vw1, vw2);
    }
}

// Main + epilogue: block a (512 threads = 16 pair-groups x 32 lanes) does the
// whole compacted b-list for receiver a, reduces in-block, then finishes the
// output row in the same block (no partials roundtrip, no third dispatch).
__global__ __launch_bounds__(512) void mainepi_kernel(
    const float* __restrict__ feat,  const float* __restrict__ coord,
    const int* __restrict__ maskraw,
    const float* __restrict__ Wm1,   const float* __restrict__ Wm2,
    const float* __restrict__ Wout0, const float* __restrict__ Wout1,
    const float* __restrict__ Wmove,
    const float* __restrict__ ws,    float* __restrict__ out)
{
    const int a = blockIdx.x;
    const int t = threadIdx.x;
    const int g = t >> 5;
    const int l = t & 31;

    // big buffer: Wm2T [192][36] during loop; red/epilogue arrays after
    __shared__ __align__(16) float big[192*36];       // 27648 B
    __shared__ __align__(16) float WT1[32*36];        // [l][j] = Wm1[(32+j)*32+l]
    __shared__ __align__(16) float E_l[33*32];
    __shared__ __align__(16) float hsh[512];
    __shared__ __align__(16) float radsh[512];
    __shared__ float cxl[NN], cyl[NN], czl[NN];
    __shared__ int   blist[NN];
    __shared__ int   wcnt[4], wbase[4];
    __shared__ float cs_part[4];
    __shared__ int   na_sh, bflag_sh, maska_sh;
    __shared__ float invc_sh;

    // ---- stage LDS ----
    for (int idx = t; idx < 6144; idx += 512){
        int r = idx / 192, o = idx - r*192;
        big[o*36 + r] = Wm2[idx];
    }
    for (int idx = t; idx < 1024; idx += 512){
        int j = idx >> 5, l2 = idx & 31;
        WT1[l2*36 + j] = Wm1[1024 + idx];
    }
    for (int idx = t; idx < 1056; idx += 512) E_l[idx] = ws[OFF_E + idx];

    if (t == 0) bflag_sh = 0;
    __syncthreads();
    if (t < 64 && (maskraw[t] & 0xFFFFFFFE)) bflag_sh = 1;
    float cs_acc = (t < NN) ? ws[OFF_CSP + t] : 0.f;
    __syncthreads();
    const bool bytemode = bflag_sh != 0;

    int m_t = 0, pfx = 0;
    if (t < NN){
        if (bytemode){
            unsigned int w = (unsigned int)maskraw[t >> 2];
            m_t = ((w >> ((t & 3) * 8)) & 0xFFu) != 0;
        } else {
            m_t = maskraw[t] != 0;
        }
        if (t == a) maska_sh = m_t;
        unsigned long long bal = __ballot(m_t != 0);
        int lane = t & 63;
        pfx = __popcll(bal & ((1ull << lane) - 1ull));
        if (lane == 0) wcnt[t >> 6] = __popcll(bal);
        #pragma unroll
        for (int off = 32; off >= 1; off >>= 1) cs_acc += __shfl_xor(cs_acc, off);
        if (lane == 0) cs_part[t >> 6] = cs_acc;
    }
    __syncthreads();
    if (t == 0){
        int s = 0;
        for (int w = 0; w < 4; w++){ wbase[w] = s; s += wcnt[w]; }
        na_sh = s;
        float cstot = cs_part[0] + cs_part[1] + cs_part[2] + cs_part[3];
        invc_sh = 1.0f / sqrtf(cstot / 100001.0f);
    }
    __syncthreads();
    if (t < NN && m_t) blist[wbase[t >> 6] + pfx] = t;
    __syncthreads();
    const int na = na_sh;
    for (int idx = t; idx < na; idx += 512){
        int bb = blist[idx];
        cxl[idx] = coord[bb*3+0];
        cyl[idx] = coord[bb*3+1];
        czl[idx] = coord[bb*3+2];
    }
    __syncthreads();

    const float inv_c = invc_sh;
    const bool mask_a = maska_sh != 0;
    const float ca0 = coord[a*3+0], ca1 = coord[a*3+1], ca2 = coord[a*3+2];
    const float sar = ws[OFF_S + a*32 + l];

    const float ISC   = 0.055814557f;  // 1/sqrt(321)
    const float IS320 = 0.055901699f;  // 1/sqrt(320)

    float acc0[4] = {0.f,0.f,0.f,0.f};
    float acc1[2][3] = {{0.f,0.f,0.f},{0.f,0.f,0.f}};

    const int cnt = mask_a ? na : 0;
    const int iters = (cnt + 15) >> 4;

    const float4* T0  = (const float4*)(ws + OFF_T0);
    const float4* TW  = (const float4*)(ws + OFF_TW);
    const float4* T1A = (const float4*)(ws + OFF_T1A);
    const float4* T1B = (const float4*)(ws + OFF_T1B);
    const float4* Wm2T4 = (const float4*)big;
    const float4* WT14  = (const float4*)WT1;

    for (int i = 0; i < iters; i++){
        int il = i*16 + g;
        bool active = il < cnt;
        int idx = active ? il : 0;
        int bb = blist[idx];
        float cmf = active ? 1.0f : 0.0f;

        float vx = ca0 - cxl[idx], vy = ca1 - cyl[idx], vz = ca2 - czl[idx];
        float nsq = vx*vx + vy*vy + vz*vz;
        float dist = sqrtf(nsq == 0.0f ? 1.0f : nsq);
        float sh1x = 1.73205081f*vx, sh1y = 1.73205081f*vy, sh1z = 1.73205081f*vz;
        float s20 = 3.87298335f*vx*vz;
        float s21 = 3.87298335f*vx*vy;
        float s22 = 2.23606798f*(vy*vy - 0.5f*(vx*vx + vz*vz));
        float s23 = 3.87298335f*vy*vz;
        float s24 = 1.93649167f*(vz*vz - vx*vx);
        float Txx = -s22*0.182574186f - s24*0.316227766f;
        float Tyy =  s22*0.365148372f;
        float Tzz = -s22*0.182574186f + s24*0.316227766f;
        float Txy =  s21*0.316227766f;
        float Txz =  s20*0.316227766f;
        float Tyz =  s23*0.316227766f;

        float m0v[4];
        #pragma unroll
        for (int j = 0; j < 4; j++){
            float4 t0 = T0[bb*128 + l + 32*j];
            m0v[j] = t0.x + vx*t0.y + vy*t0.z + vz*t0.w;
        }

        float vcen = 0.727272727f * (float)(l + 1);
        float ddr = (dist - vcen) * 1.375f;
        float rl = __expf(-ddr*ddr) * 0.892857143f * cmf;
        radsh[g*32 + l] = rl;
        float radw = 0.f;
        {
            const float4* rv = (const float4*)radsh + g*8;
            const float4* wv = WT14 + l*9;
            #pragma unroll
            for (int j4 = 0; j4 < 8; j4++){
                float4 r4 = rv[j4];
                float4 w4 = wv[j4];
                radw += r4.x*w4.x + r4.y*w4.y + r4.z*w4.z + r4.w*w4.w;
            }
        }

        int ir = a - bb;
        if (ir > 16 || ir < -16) ir = 0;
        if (!active) ir = 0;
        ir += 16;
        float4 tw = TW[bb*32 + l];
        float msgblk = tw.x + vx*tw.y + vy*tw.z + vz*tw.w;
        float pre = (E_l[ir*32 + l] + sar + radw + msgblk*ISC) * IS320;
        float h = pre / (1.0f + __expf(-pre)) * inv_c;
        hsh[g*32 + l] = h;

        float gg[6] = {0,0,0,0,0,0};
        {
            const float4* hv = (const float4*)hsh + g*8;
            #pragma unroll
            for (int r4 = 0; r4 < 8; r4++){
                float4 h4 = hv[r4];
                #pragma unroll
                for (int k = 0; k < 6; k++){
                    float4 w4 = Wm2T4[(l + 32*k)*9 + r4];
                    gg[k] += h4.x*w4.x + h4.y*w4.y + h4.z*w4.z + h4.w*w4.w;
                }
            }
        }
        #pragma unroll
        for (int k = 0; k < 6; k++) gg[k] *= cmf;

        #pragma unroll
        for (int j = 0; j < 4; j++) acc0[j] += m0v[j] * gg[j];

        #pragma unroll
        for (int jj = 0; jj < 2; jj++){
            float4 a1 = T1A[bb*64 + l + 32*jj];
            float4 u1 = T1B[bb*64 + l + 32*jj];
            float gv = gg[4+jj];
            float m10 = a1.x + sh1x*a1.w + Txx*u1.x + Txy*u1.y + Txz*u1.z;
            float m11 = a1.y + sh1y*a1.w + Txy*u1.x + Tyy*u1.y + Tyz*u1.z;
            float m12 = a1.z + sh1z*a1.w + Txz*u1.x + Tyz*u1.y + Tzz*u1.z;
            acc1[jj][0] += m10 * gv;
            acc1[jj][1] += m11 * gv;
            acc1[jj][2] += m12 * gv;
        }
    }

    // wave-internal combine of the two 32-lane groups (same channels)
    #pragma unroll
    for (int j = 0; j < 4; j++) acc0[j] += __shfl_xor(acc0[j], 32);
    #pragma unroll
    for (int jj = 0; jj < 2; jj++)
        #pragma unroll
        for (int k = 0; k < 3; k++) acc1[jj][k] += __shfl_xor(acc1[jj][k], 32);

    __syncthreads();   // done with Wm2T; alias big[] for reductions/epilogue
    float* red0  = big;          // [8][128]
    float* red1  = big + 1024;   // [8][192]
    float* aggr  = big + 2560;   // [320]
    float* r0_l  = big + 2880;   // [128]
    float* r1_l  = big + 3008;   // [192]
    float* f1_l  = big + 3200;   // [192]
    float* stats = big + 3392;   // [8]

    const int wv = t >> 6;
    if ((t & 63) < 32){
        #pragma unroll
        for (int j = 0; j < 4; j++) red0[wv*128 + l + 32*j] = acc0[j];
        #pragma unroll
        for (int jj = 0; jj < 2; jj++)
            #pragma unroll
            for (int k = 0; k < 3; k++) red1[wv*192 + (l + 32*jj)*3 + k] = acc1[jj][k];
    }
    __syncthreads();

    const float cntv = mask_a ? (float)na : 0.0f;
    const float inv = (cntv > 1.0f) ? 1.0f / (cntv + 1e-6f) : 0.0f;
    const float SCALE = 0.055814557f * 0.176776695f;  // 1/sqrt(321)/sqrt(32)

    for (int idx = t; idx < 320; idx += 512){
        float s = 0.f;
        if (idx < 128){
            #pragma unroll
            for (int w = 0; w < 8; w++) s += red0[w*128 + idx];
        } else {
            #pragma unroll
            for (int w = 0; w < 8; w++) s += red1[w*192 + idx - 128];
        }
        aggr[idx] = s * SCALE * inv;
    }
    __syncthreads();

    if (t < 128){
        float f = 0.f;
        #pragma unroll 4
        for (int c = 0; c < 128; c++) f += aggr[c] * Wout0[c*128 + t];
        r0_l[t] = feat[a*320 + t] + f * 0.088388348f;   // 1/sqrt(128)
    } else if (t < 192){
        int o = t - 128;
        float fv0 = 0.f, fv1 = 0.f, fv2 = 0.f;
        #pragma unroll 4
        for (int c = 0; c < 64; c++){
            float w = Wout1[c*64 + o];
            fv0 += aggr[128 + c*3+0] * w;
            fv1 += aggr[128 + c*3+1] * w;
            fv2 += aggr[128 + c*3+2] * w;
        }
        fv0 *= 0.125f; fv1 *= 0.125f; fv2 *= 0.125f;
        f1_l[o*3+0] = fv0; f1_l[o*3+1] = fv1; f1_l[o*3+2] = fv2;
        r1_l[o*3+0] = feat[a*320 + 128 + o*3+0] + fv0;
        r1_l[o*3+1] = feat[a*320 + 128 + o*3+1] + fv1;
        r1_l[o*3+2] = feat[a*320 + 128 + o*3+2] + fv2;
    }
    __syncthreads();

    if (t < 64){
        float x0 = r0_l[t], x1 = r0_l[t+64];
        float s0 = x0 + x1, sq = x0*x0 + x1*x1;
        float y0 = r1_l[t*3], y1 = r1_l[t*3+1], y2 = r1_l[t*3+2];
        float s1 = y0*y0 + y1*y1 + y2*y2;
        float wm = Wmove[t];
        float d0 = f1_l[t*3+0]*wm, d1 = f1_l[t*3+1]*wm, d2 = f1_l[t*3+2]*wm;
        #pragma unroll
        for (int off = 32; off >= 1; off >>= 1){
            s0 += __shfl_xor(s0, off);
            sq += __shfl_xor(sq, off);
            s1 += __shfl_xor(s1, off);
            d0 += __shfl_xor(d0, off);
            d1 += __shfl_xor(d1, off);
            d2 += __shfl_xor(d2, off);
        }
        if (t == 0){
            float mu = s0 * (1.0f/128.0f);
            float var = sq * (1.0f/128.0f) - mu*mu;
            stats[0] = mu;
            stats[1] = 1.0f / sqrtf(var + 1e-6f);
            stats[2] = 1.0f / sqrtf(s1 * (1.0f/192.0f) + 1e-6f);
            stats[3] = d0; stats[4] = d1; stats[5] = d2;
        }
    }
    __syncthreads();

    float* orow = out + a*323;
    for (int idx = t; idx < 323; idx += 512){
        float v;
        if (idx < 128)      v = (r0_l[idx] - stats[0]) * stats[1];
        else if (idx < 320) v = r1_l[idx-128] * stats[2];
        else                v = coord[a*3 + (idx-320)] + 0.000125f * stats[3 + (idx-320)];
        orow[idx] = v;
    }
}

extern "C" void kernel_launch(void* const* d_in, const int* in_sizes, int n_in,
                              void* d_out, int out_size, void* d_ws, size_t ws_size,
                              hipStream_t stream)
{
    const float* feat  = (const float*)d_in[0];
    const float* coord = (const float*)d_in[1];
    const float* W0    = (const float*)d_in[2];
    const float* W1    = (const float*)d_in[3];
    const float* tbl   = (const float*)d_in[4];
    const float* Wm1   = (const float*)d_in[5];
    const float* Wm2   = (const float*)d_in[6];
    const float* Wout0 = (const float*)d_in[7];
    const float* Wout1 = (const float*)d_in[8];
    const float* Wmove = (const float*)d_in[9];
    const int*   mask  = (const int*)d_in[10];
    float* ws  = (float*)d_ws;
    float* out = (float*)d_out;

    precompute_kernel<<<NN + 256, 256, 0, stream>>>(feat, W0, W1, tbl, Wm1, ws);
    mainepi_kernel<<<NN, 512, 0, stream>>>(feat, coord, mask, Wm1, Wm2,
                                           Wout0, Wout1, Wmove, ws, out);
}

// Round 15
// 176.505 us; speedup vs baseline: 1.3307x; 1.0222x over previous
//
#include <hip/hip_runtime.h>
#include <math.h>

#define NN 256

// ---- workspace layout ----
// Tables T0/TW/T1A/T1B are bf16-packed: one uint2 per entry = 4 bf16 values.
// Offsets in 4-byte units (uints/floats interchangeably).
#define U_T0    0        // [256][128] uint2 {P0B,V0x | V0y,V0z}
#define U_TW    65536    // [256][32]  uint2 {PW,VWx | VWy,VWz}
#define U_T1A   81920    // [256][64]  uint2 {A1k0,A1k1 | A1k2,P1B}
#define U_T1B   114688   // [256][64]  uint2 {U1x,U1y | U1z,0}
#define OFF_S   147456   // [256][32] float  s_in[a] @ Wm1[64:192]
#define OFF_E   155648   // [33][32]  float  embed_tbl @ Wm1[0:32]
#define OFF_CSP 156704   // [256]     float  csilu partial sums

__device__ __forceinline__ unsigned tobf(float f){
    unsigned x = __float_as_uint(f);
    return (x + 0x7fffu + ((x >> 16) & 1u)) >> 16;   // RNE
}
__device__ __forceinline__ unsigned pack2(float lo, float hi){
    return tobf(lo) | (tobf(hi) << 16);
}
__device__ __forceinline__ float bflo(unsigned u){ return __uint_as_float(u << 16); }
__device__ __forceinline__ float bfhi(unsigned u){ return __uint_as_float(u & 0xffff0000u); }

__device__ __forceinline__ float my_erfinv(float x){
    float w = -logf((1.0f - x) * (1.0f + x));
    float p;
    if (w < 5.0f) {
        w = w - 2.5f;
        p = 2.81022636e-08f;
        p = 3.43273939e-07f + p*w;
        p = -3.5233877e-06f + p*w;
        p = -4.39150654e-06f + p*w;
        p = 0.00021858087f  + p*w;
        p = -0.00125372503f + p*w;
        p = -0.00417768164f + p*w;
        p = 0.246640727f    + p*w;
        p = 1.50140941f     + p*w;
    } else {
        w = sqrtf(w) - 3.0f;
        p = -0.000200214257f;
        p = 0.000100950558f + p*w;
        p = 0.00134934322f  + p*w;
        p = -0.00367342844f + p*w;
        p = 0.00573950773f  + p*w;
        p = -0.0076224613f  + p*w;
        p = 0.00943887047f  + p*w;
        p = 1.00167406f     + p*w;
        p = 2.83297682f     + p*w;
    }
    return p * x;
}

// grid = 512: blocks [0,256) build per-node tables; [256,512) csilu partials.
__global__ __launch_bounds__(256) void precompute_kernel(
    const float* __restrict__ feat, const float* __restrict__ W0,
    const float* __restrict__ W1, const float* __restrict__ tbl,
    const float* __restrict__ Wm1, float* __restrict__ ws)
{
    int b = blockIdx.x, t = threadIdx.x;
    unsigned int* wsu = (unsigned int*)ws;
    __shared__ float s_l[128], v_l[192];
    __shared__ float P0B_l[128], V0_l[3][128];
    __shared__ float red[256];

    if (b >= NN){
        int bi = b - NN;
        int lo = bi * 391;
        int hi = lo + 391; if (hi > 100001) hi = 100001;
        float acc = 0.f;
        for (int i = lo + t; i < hi; i += 256){
            float u = -0.999999f + (float)i * (1.999998f / 100000.0f);
            float z = 1.41421356237f * my_erfinv(u);
            float s = z / (1.0f + __expf(-z));
            acc += s * s;
        }
        red[t] = acc;
        __syncthreads();
        for (int off = 128; off >= 1; off >>= 1){
            if (t < off) red[t] += red[t + off];
            __syncthreads();
        }
        if (t == 0) ws[OFF_CSP + bi] = red[0];
        return;
    }

    for (int idx = t; idx < 320; idx += 256){
        float val = feat[b*320 + idx];
        if (idx < 128) s_l[idx] = val; else v_l[idx-128] = val;
    }
    __syncthreads();
    if (t < 128){
        int o = t;
        float p0 = W0[192*128 + o];
        #pragma unroll 4
        for (int i = 0; i < 128; i++){
            float s = s_l[i];
            p0 += s * (W0[i*128 + o] + W0[(193+i)*128 + o]);
        }
        float v0d[3];
        for (int d = 0; d < 3; d++){
            float v0 = 0.f;
            #pragma unroll 4
            for (int c = 0; c < 64; c++) v0 += v_l[c*3+d] * W0[(128+c)*128 + o];
            v0d[d] = v0;
        }
        P0B_l[o] = p0;
        V0_l[0][o] = v0d[0]; V0_l[1][o] = v0d[1]; V0_l[2][o] = v0d[2];
        ((uint2*)(wsu + U_T0))[b*128 + o] =
            make_uint2(pack2(p0, v0d[0]), pack2(v0d[1], v0d[2]));
    } else if (t < 192){
        int o = t - 128;
        float ac[3];
        for (int k = 0; k < 3; k++){
            float s = 0.f;
            #pragma unroll 4
            for (int c = 0; c < 64; c++){
                float v = v_l[c*3+k];
                s += v * (W1[c*64 + o] + W1[(257+c)*64 + o]);
            }
            ac[k] = s;
        }
        float p1 = W1[256*64 + o];
        #pragma unroll 4
        for (int c = 0; c < 128; c++) p1 += s_l[c] * W1[(64+c)*64 + o];
        float u1[3];
        for (int d = 0; d < 3; d++){
            float s = 0.f;
            #pragma unroll 4
            for (int c = 0; c < 64; c++) s += v_l[c*3+d] * W1[(192+c)*64 + o];
            u1[d] = 1.73205081f * s;
        }
        ((uint2*)(wsu + U_T1A))[b*64 + o] =
            make_uint2(pack2(ac[0], ac[1]), pack2(ac[2], p1));
        ((uint2*)(wsu + U_T1B))[b*64 + o] =
            make_uint2(pack2(u1[0], u1[1]), pack2(u1[2], 0.f));
    } else if (t < 224){
        int r = t - 192;
        float s = 0.f;
        #pragma unroll 4
        for (int i = 0; i < 128; i++) s += s_l[i] * Wm1[(64+i)*32 + r];
        ws[OFF_S + b*32 + r] = s;
        if (b < 33){
            float e = 0.f;
            #pragma unroll 4
            for (int k = 0; k < 32; k++) e += tbl[b*32 + k] * Wm1[k*32 + r];
            ws[OFF_E + b*32 + r] = e;
        }
    }
    __syncthreads();
    if (t < 32){
        int r = t;
        float pw = 0.f, vw0 = 0.f, vw1 = 0.f, vw2 = 0.f;
        #pragma unroll 4
        for (int o = 0; o < 128; o++){
            float w = Wm1[(192+o)*32 + r];
            pw  += P0B_l[o]  * w;
            vw0 += V0_l[0][o]* w;
            vw1 += V0_l[1][o]* w;
            vw2 += V0_l[2][o]* w;
        }
        ((uint2*)(wsu + U_TW))[b*32 + r] =
            make_uint2(pack2(pw, vw0), pack2(vw1, vw2));
    }
}

// Main + epilogue: block a (512 threads = 16 pair-groups x 32 lanes) does the
// whole compacted b-list for receiver a, reduces in-block, then finishes the
// output row. Tables are bf16-packed (half the HBM lines of fp32).
__global__ __launch_bounds__(512) void mainepi_kernel(
    const float* __restrict__ feat,  const float* __restrict__ coord,
    const int* __restrict__ maskraw,
    const float* __restrict__ Wm1,   const float* __restrict__ Wm2,
    const float* __restrict__ Wout0, const float* __restrict__ Wout1,
    const float* __restrict__ Wmove,
    const float* __restrict__ ws,    float* __restrict__ out)
{
    const int a = blockIdx.x;
    const int t = threadIdx.x;
    const int g = t >> 5;
    const int l = t & 31;
    const unsigned int* wsu = (const unsigned int*)ws;

    // big buffer: Wm2T [192][36] during loop; red/epilogue arrays after
    __shared__ __align__(16) float big[192*36];       // 27648 B
    __shared__ __align__(16) float WT1[32*36];        // [l][j] = Wm1[(32+j)*32+l]
    __shared__ __align__(16) float E_l[33*32];
    __shared__ __align__(16) float hsh[512];
    __shared__ __align__(16) float radsh[512];
    __shared__ float cxl[NN], cyl[NN], czl[NN];
    __shared__ int   blist[NN];
    __shared__ int   wcnt[4], wbase[4];
    __shared__ float cs_part[4];
    __shared__ int   na_sh, bflag_sh, maska_sh;
    __shared__ float invc_sh;

    // ---- stage LDS ----
    for (int idx = t; idx < 6144; idx += 512){
        int r = idx / 192, o = idx - r*192;
        big[o*36 + r] = Wm2[idx];
    }
    for (int idx = t; idx < 1024; idx += 512){
        int j = idx >> 5, l2 = idx & 31;
        WT1[l2*36 + j] = Wm1[1024 + idx];
    }
    for (int idx = t; idx < 1056; idx += 512) E_l[idx] = ws[OFF_E + idx];

    if (t == 0) bflag_sh = 0;
    __syncthreads();
    if (t < 64 && (maskraw[t] & 0xFFFFFFFE)) bflag_sh = 1;
    float cs_acc = (t < NN) ? ws[OFF_CSP + t] : 0.f;
    __syncthreads();
    const bool bytemode = bflag_sh != 0;

    int m_t = 0, pfx = 0;
    if (t < NN){
        if (bytemode){
            unsigned int w = (unsigned int)maskraw[t >> 2];
            m_t = ((w >> ((t & 3) * 8)) & 0xFFu) != 0;
        } else {
            m_t = maskraw[t] != 0;
        }
        if (t == a) maska_sh = m_t;
        unsigned long long bal = __ballot(m_t != 0);
        int lane = t & 63;
        pfx = __popcll(bal & ((1ull << lane) - 1ull));
        if (lane == 0) wcnt[t >> 6] = __popcll(bal);
        #pragma unroll
        for (int off = 32; off >= 1; off >>= 1) cs_acc += __shfl_xor(cs_acc, off);
        if (lane == 0) cs_part[t >> 6] = cs_acc;
    }
    __syncthreads();
    if (t == 0){
        int s = 0;
        for (int w = 0; w < 4; w++){ wbase[w] = s; s += wcnt[w]; }
        na_sh = s;
        float cstot = cs_part[0] + cs_part[1] + cs_part[2] + cs_part[3];
        invc_sh = 1.0f / sqrtf(cstot / 100001.0f);
    }
    __syncthreads();
    if (t < NN && m_t) blist[wbase[t >> 6] + pfx] = t;
    __syncthreads();
    const int na = na_sh;
    for (int idx = t; idx < na; idx += 512){
        int bb = blist[idx];
        cxl[idx] = coord[bb*3+0];
        cyl[idx] = coord[bb*3+1];
        czl[idx] = coord[bb*3+2];
    }
    __syncthreads();

    const float inv_c = invc_sh;
    const bool mask_a = maska_sh != 0;
    const float ca0 = coord[a*3+0], ca1 = coord[a*3+1], ca2 = coord[a*3+2];
    const float sar = ws[OFF_S + a*32 + l];

    const float ISC   = 0.055814557f;  // 1/sqrt(321)
    const float IS320 = 0.055901699f;  // 1/sqrt(320)

    float acc0[4] = {0.f,0.f,0.f,0.f};
    float acc1[2][3] = {{0.f,0.f,0.f},{0.f,0.f,0.f}};

    const int cnt = mask_a ? na : 0;
    const int iters = (cnt + 15) >> 4;

    const uint2* T0h  = (const uint2*)(wsu + U_T0);
    const uint2* TWh  = (const uint2*)(wsu + U_TW);
    const uint2* T1Ah = (const uint2*)(wsu + U_T1A);
    const uint2* T1Bh = (const uint2*)(wsu + U_T1B);
    const float4* Wm2T4 = (const float4*)big;
    const float4* WT14  = (const float4*)WT1;

    for (int i = 0; i < iters; i++){
        int il = i*16 + g;
        bool active = il < cnt;
        int idx = active ? il : 0;
        int bb = blist[idx];
        float cmf = active ? 1.0f : 0.0f;

        float vx = ca0 - cxl[idx], vy = ca1 - cyl[idx], vz = ca2 - czl[idx];
        float nsq = vx*vx + vy*vy + vz*vz;
        float dist = sqrtf(nsq == 0.0f ? 1.0f : nsq);
        float sh1x = 1.73205081f*vx, sh1y = 1.73205081f*vy, sh1z = 1.73205081f*vz;
        float s20 = 3.87298335f*vx*vz;
        float s21 = 3.87298335f*vx*vy;
        float s22 = 2.23606798f*(vy*vy - 0.5f*(vx*vx + vz*vz));
        float s23 = 3.87298335f*vy*vz;
        float s24 = 1.93649167f*(vz*vz - vx*vx);
        float Txx = -s22*0.182574186f - s24*0.316227766f;
        float Tyy =  s22*0.365148372f;
        float Tzz = -s22*0.182574186f + s24*0.316227766f;
        float Txy =  s21*0.316227766f;
        float Txz =  s20*0.316227766f;
        float Tyz =  s23*0.316227766f;

        float m0v[4];
        #pragma unroll
        for (int j = 0; j < 4; j++){
            uint2 q = T0h[bb*128 + l + 32*j];
            float p0b = bflo(q.x), v0x = bfhi(q.x);
            float v0y = bflo(q.y), v0z = bfhi(q.y);
            m0v[j] = p0b + vx*v0x + vy*v0y + vz*v0z;
        }

        float vcen = 0.727272727f * (float)(l + 1);
        float ddr = (dist - vcen) * 1.375f;
        float rl = __expf(-ddr*ddr) * 0.892857143f * cmf;
        radsh[g*32 + l] = rl;
        float radw = 0.f;
        {
            const float4* rv = (const float4*)radsh + g*8;
            const float4* wv = WT14 + l*9;
            #pragma unroll
            for (int j4 = 0; j4 < 8; j4++){
                float4 r4 = rv[j4];
                float4 w4 = wv[j4];
                radw += r4.x*w4.x + r4.y*w4.y + r4.z*w4.z + r4.w*w4.w;
            }
        }

        int ir = a - bb;
        if (ir > 16 || ir < -16) ir = 0;
        if (!active) ir = 0;
        ir += 16;
        uint2 qw = TWh[bb*32 + l];
        float msgblk = bflo(qw.x) + vx*bfhi(qw.x) + vy*bflo(qw.y) + vz*bfhi(qw.y);
        float pre = (E_l[ir*32 + l] + sar + radw + msgblk*ISC) * IS320;
        float h = pre / (1.0f + __expf(-pre)) * inv_c;
        hsh[g*32 + l] = h;

        float gg[6] = {0,0,0,0,0,0};
        {
            const float4* hv = (const float4*)hsh + g*8;
            #pragma unroll
            for (int r4 = 0; r4 < 8; r4++){
                float4 h4 = hv[r4];
                #pragma unroll
                for (int k = 0; k < 6; k++){
                    float4 w4 = Wm2T4[(l + 32*k)*9 + r4];
                    gg[k] += h4.x*w4.x + h4.y*w4.y + h4.z*w4.z + h4.w*w4.w;
                }
            }
        }
        #pragma unroll
        for (int k = 0; k < 6; k++) gg[k] *= cmf;

        #pragma unroll
        for (int j = 0; j < 4; j++) acc0[j] += m0v[j] * gg[j];

        #pragma unroll
        for (int jj = 0; jj < 2; jj++){
            uint2 qa = T1Ah[bb*64 + l + 32*jj];
            uint2 qb = T1Bh[bb*64 + l + 32*jj];
            float a1x = bflo(qa.x), a1y = bfhi(qa.x);
            float a1z = bflo(qa.y), p1b = bfhi(qa.y);
            float u1x = bflo(qb.x), u1y = bfhi(qb.x);
            float u1z = bflo(qb.y);
            float gv = gg[4+jj];
            float m10 = a1x + sh1x*p1b + Txx*u1x + Txy*u1y + Txz*u1z;
            float m11 = a1y + sh1y*p1b + Txy*u1x + Tyy*u1y + Tyz*u1z;
            float m12 = a1z + sh1z*p1b + Txz*u1x + Tyz*u1y + Tzz*u1z;
            acc1[jj][0] += m10 * gv;
            acc1[jj][1] += m11 * gv;
            acc1[jj][2] += m12 * gv;
        }
    }

    // wave-internal combine of the two 32-lane groups (same channels)
    #pragma unroll
    for (int j = 0; j < 4; j++) acc0[j] += __shfl_xor(acc0[j], 32);
    #pragma unroll
    for (int jj = 0; jj < 2; jj++)
        #pragma unroll
        for (int k = 0; k < 3; k++) acc1[jj][k] += __shfl_xor(acc1[jj][k], 32);

    __syncthreads();   // done with Wm2T; alias big[] for reductions/epilogue
    float* red0  = big;          // [8][128]
    float* red1  = big + 1024;   // [8][192]
    float* aggr  = big + 2560;   // [320]
    float* r0_l  = big + 2880;   // [128]
    float* r1_l  = big + 3008;   // [192]
    float* f1_l  = big + 3200;   // [192]
    float* stats = big + 3392;   // [8]

    const int wv = t >> 6;
    if ((t & 63) < 32){
        #pragma unroll
        for (int j = 0; j < 4; j++) red0[wv*128 + l + 32*j] = acc0[j];
        #pragma unroll
        for (int jj = 0; jj < 2; jj++)
            #pragma unroll
            for (int k = 0; k < 3; k++) red1[wv*192 + (l + 32*jj)*3 + k] = acc1[jj][k];
    }
    __syncthreads();

    const float cntv = mask_a ? (float)na : 0.0f;
    const float inv = (cntv > 1.0f) ? 1.0f / (cntv + 1e-6f) : 0.0f;
    const float SCALE = 0.055814557f * 0.176776695f;  // 1/sqrt(321)/sqrt(32)

    for (int idx = t; idx < 320; idx += 512){
        float s = 0.f;
        if (idx < 128){
            #pragma unroll
            for (int w = 0; w < 8; w++) s += red0[w*128 + idx];
        } else {
            #pragma unroll
            for (int w = 0; w < 8; w++) s += red1[w*192 + idx - 128];
        }
        aggr[idx] = s * SCALE * inv;
    }
    __syncthreads();

    if (t < 128){
        float f = 0.f;
        #pragma unroll 4
        for (int c = 0; c < 128; c++) f += aggr[c] * Wout0[c*128 + t];
        r0_l[t] = feat[a*320 + t] + f * 0.088388348f;   // 1/sqrt(128)
    } else if (t < 192){
        int o = t - 128;
        float fv0 = 0.f, fv1 = 0.f, fv2 = 0.f;
        #pragma unroll 4
        for (int c = 0; c < 64; c++){
            float w = Wout1[c*64 + o];
            fv0 += aggr[128 + c*3+0] * w;
            fv1 += aggr[128 + c*3+1] * w;
            fv2 += aggr[128 + c*3+2] * w;
        }
        fv0 *= 0.125f; fv1 *= 0.125f; fv2 *= 0.125f;
        f1_l[o*3+0] = fv0; f1_l[o*3+1] = fv1; f1_l[o*3+2] = fv2;
        r1_l[o*3+0] = feat[a*320 + 128 + o*3+0] + fv0;
        r1_l[o*3+1] = feat[a*320 + 128 + o*3+1] + fv1;
        r1_l[o*3+2] = feat[a*320 + 128 + o*3+2] + fv2;
    }
    __syncthreads();

    if (t < 64){
        float x0 = r0_l[t], x1 = r0_l[t+64];
        float s0 = x0 + x1, sq = x0*x0 + x1*x1;
        float y0 = r1_l[t*3], y1 = r1_l[t*3+1], y2 = r1_l[t*3+2];
        float s1 = y0*y0 + y1*y1 + y2*y2;
        float wm = Wmove[t];
        float d0 = f1_l[t*3+0]*wm, d1 = f1_l[t*3+1]*wm, d2 = f1_l[t*3+2]*wm;
        #pragma unroll
        for (int off = 32; off >= 1; off >>= 1){
            s0 += __shfl_xor(s0, off);
            sq += __shfl_xor(sq, off);
            s1 += __shfl_xor(s1, off);
            d0 += __shfl_xor(d0, off);
            d1 += __shfl_xor(d1, off);
            d2 += __shfl_xor(d2, off);
        }
        if (t == 0){
            float mu = s0 * (1.0f/128.0f);
            float var = sq * (1.0f/128.0f) - mu*mu;
            stats[0] = mu;
            stats[1] = 1.0f / sqrtf(var + 1e-6f);
            stats[2] = 1.0f / sqrtf(s1 * (1.0f/192.0f) + 1e-6f);
            stats[3] = d0; stats[4] = d1; stats[5] = d2;
        }
    }
    __syncthreads();

    float* orow = out + a*323;
    for (int idx = t; idx < 323; idx += 512){
        float v;
        if (idx < 128)      v = (r0_l[idx] - stats[0]) * stats[1];
        else if (idx < 320) v = r1_l[idx-128] * stats[2];
        else                v = coord[a*3 + (idx-320)] + 0.000125f * stats[3 + (idx-320)];
        orow[idx] = v;
    }
}

extern "C" void kernel_launch(void* const* d_in, const int* in_sizes, int n_in,
                              void* d_out, int out_size, void* d_ws, size_t ws_size,
                              hipStream_t stream)
{
    const float* feat  = (const float*)d_in[0];
    const float* coord = (const float*)d_in[1];
    const float* W0    = (const float*)d_in[2];
    const float* W1    = (const float*)d_in[3];
    const float* tbl   = (const float*)d_in[4];
    const float* Wm1   = (const float*)d_in[5];
    const float* Wm2   = (const float*)d_in[6];
    const float* Wout0 = (const float*)d_in[7];
    const float* Wout1 = (const float*)d_in[8];
    const float* Wmove = (const float*)d_in[9];
    const int*   mask  = (const int*)d_in[10];
    float* ws  = (float*)d_ws;
    float* out = (float*)d_out;

    precompute_kernel<<<NN + 256, 256, 0, stream>>>(feat, W0, W1, tbl, Wm1, ws);
    mainepi_kernel<<<NN, 512, 0, stream>>>(feat, coord, mask, Wm1, Wm2,
                                           Wout0, Wout1, Wmove, ws, out);
}